// Round 3
// baseline (4287.019 us; speedup 1.0000x reference)
//
#include <hip/hip_runtime.h>
#include <math.h>

typedef __bf16 bf16;
typedef __bf16 bf16x8 __attribute__((ext_vector_type(8)));
typedef float f32x4 __attribute__((ext_vector_type(4)));

#define ZDIM 17728
#define HIDN 4096
#define BSZ 128
#define KC1 16   // K-split chunks for GEMM1 (554 k-steps of 32)
#define KC2 4    // K-split chunks for GEMM2 (128 k-steps of 32)

// ---------- cast + transpose: src (K x N) f32 -> dst (N x K) bf16 ----------
__global__ void k_cast_transpose(const float* __restrict__ src, bf16* __restrict__ dst,
                                 int K, int N) {
  __shared__ float t[64][33];
  int tx = threadIdx.x, ty = threadIdx.y;  // 32 x 8
  int n0 = blockIdx.x * 32, k0 = blockIdx.y * 64;
#pragma unroll
  for (int i = 0; i < 64; i += 8)
    t[ty + i][tx] = src[(size_t)(k0 + ty + i) * N + (n0 + tx)];
  __syncthreads();
#pragma unroll
  for (int i = 0; i < 32; i += 8) {
    int nl = ty + i;
    union { bf16 h[2]; unsigned u; } p;
    p.h[0] = (bf16)t[2 * tx][nl];
    p.h[1] = (bf16)t[2 * tx + 1][nl];
    *(unsigned*)&dst[(size_t)(n0 + nl) * K + k0 + 2 * tx] = p.u;
  }
}

// ---------- build z0: one block per batch row, LDS-staged gather ----------
__global__ void k_build_z0(const float* __restrict__ input_freq, const int* __restrict__ seq,
                           const int* __restrict__ uid, const float* __restrict__ fuse,
                           const int* __restrict__ n_poi_p,
                           float* __restrict__ z, bf16* __restrict__ zb) {
  __shared__ float X[64 * 129];  // X[l][d], padded
  int b = blockIdx.x, tid = threadIdx.x;  // 256 threads
  float* zr = z + (size_t)b * ZDIM;
  bf16* zbr = zb + (size_t)b * ZDIM;
  // part 1: freq tile (9408 = 3 x 3136)
  for (int n = tid; n < 9408; n += 256) {
    float v = input_freq[b * 3136 + (n % 3136)];
    zr[n] = v; zbr[n] = (bf16)v;
  }
  // part 2: stage 64 fuse rows coalesced: thread t -> row t>>2, cols (t&3)*32..
  {
    int l = tid >> 2, c0 = (tid & 3) * 32;
    const float* srcr = fuse + (size_t)seq[b * 64 + l] * 128 + c0;
    float* dstr = X + l * 129 + c0;
#pragma unroll
    for (int i = 0; i < 32; i += 4)
      *(f32x4*)&dstr[i] = *(const f32x4*)&srcr[i];
  }
  __syncthreads();
  for (int m = tid; m < 8192; m += 256) {
    int d = m >> 6, l = m & 63;
    float v = X[l * 129 + d];
    zr[9408 + m] = v; zbr[9408 + m] = (bf16)v;
  }
  // part 3: user embedding row
  if (tid < 128) {
    float v = fuse[(size_t)(n_poi_p[0] + uid[b]) * 128 + tid];
    zr[17600 + tid] = v; zbr[17600 + tid] = (bf16)v;
  }
}

// ---------- time grid + sin/cos embedding: E[12][128][6] ----------
__global__ void k_build_emb(const float* __restrict__ cur, const float* __restrict__ tar,
                            float* __restrict__ E) {
  int b = threadIdx.x;  // 128 threads
  const float P[3] = {24.0f, 7.0f, 365.0f};
  const float TWO_PI = 6.283185307179586f;
  float t[3];
  for (int c = 0; c < 3; ++c) t[c] = cur[b * 3 + c];
  int r = 0;
  for (int j = 0; j < 3; ++j) {
    float s = cur[b * 3 + j], e = tar[b * 3 + j];
    bool wrap = s > e;
    float ea = wrap ? (e + P[j]) : e;
    for (int k = 0; k < 4; ++k) {
      float frac = (float)k / 3.0f;
      float v = s + (ea - s) * frac;
      if (wrap) v = v - floorf(v / P[j]) * P[j];
      t[j] = v;
      for (int c = 0; c < 3; ++c) {
        float ph = TWO_PI * t[c] / P[c];
        E[(r * BSZ + b) * 6 + c] = sinf(ph);
        E[(r * BSZ + b) * 6 + 3 + c] = cosf(ph);
      }
      ++r;
    }
  }
}

// ---------- barrier-free register GEMM partial ----------
// A: BSZ x Kdim row-major bf16. Bt: N x Kdim row-major bf16 (B transposed).
// Output partial P[kc]: BSZ x Nout f32, P[kc][m][n] = sum over k-chunk A[m][k]*Bt[n][k].
// Block: 256 thr / 4 waves; wave w owns 16 N-rows; block tile = 128(M) x 64(N).
// No LDS, no barriers: B-frags + A-frags loaded straight to VGPRs in MFMA layout;
// compiler software-pipelines with fine-grained vmcnt (no barrier = no vmcnt(0) drain).
__global__ __launch_bounds__(256, 4) void k_gemm_rr(const bf16* __restrict__ A,
                                                    const bf16* __restrict__ Bt,
                                                    float* __restrict__ P,
                                                    int Kdim, int Nout,
                                                    int base, int rem) {
  const int tid = threadIdx.x;
  const int w = tid >> 6, lane = tid & 63;
  const int q = lane >> 4, r = lane & 15;
  const int nt = blockIdx.x, kc = blockIdx.y;
  const int nsteps = base + (kc < rem ? 1 : 0);
  const long kstart = ((long)kc * base + (kc < rem ? kc : rem)) * 32;

  const int n0 = nt * 64 + w * 16 + r;
  const bf16* pB = Bt + (size_t)n0 * Kdim + kstart + q * 8;
  const bf16* pA[8];
#pragma unroll
  for (int mb = 0; mb < 8; ++mb)
    pA[mb] = A + (size_t)(mb * 16 + r) * Kdim + kstart + q * 8;

  f32x4 acc[8] = {};
#pragma unroll 2
  for (int s = 0; s < nsteps; ++s) {
    bf16x8 bfr = *(const bf16x8*)pB;
    bf16x8 af[8];
#pragma unroll
    for (int mb = 0; mb < 8; ++mb) af[mb] = *(const bf16x8*)pA[mb];
#pragma unroll
    for (int mb = 0; mb < 8; ++mb)
      acc[mb] = __builtin_amdgcn_mfma_f32_16x16x32_bf16(af[mb], bfr, acc[mb], 0, 0, 0);
    pB += 32;
#pragma unroll
    for (int mb = 0; mb < 8; ++mb) pA[mb] += 32;
  }

  float* Pk = P + (size_t)kc * (BSZ * (size_t)Nout);
#pragma unroll
  for (int mb = 0; mb < 8; ++mb) {
#pragma unroll
    for (int reg = 0; reg < 4; ++reg) {
      int m = mb * 16 + q * 4 + reg;
      Pk[(size_t)m * Nout + n0] = acc[mb][reg];
    }
  }
}

// ---------- reduce partials + b1 + emb-correction + tanh -> Hb (bf16) ----------
__global__ void k_epi1(const float* __restrict__ P, const float* __restrict__ b1,
                       const float* __restrict__ W1, const float* __restrict__ E,
                       int step, bf16* __restrict__ Hb) {
  int idx = blockIdx.x * 256 + threadIdx.x;  // 128*4096
  int b = idx >> 12, n = idx & 4095;
  float s = b1[n];
#pragma unroll
  for (int c = 0; c < KC1; ++c) s += P[((size_t)c * BSZ + b) * HIDN + n];
  const float* e0 = E + ((size_t)step * BSZ + b) * 6;
  const float* e1 = e0 + BSZ * 6;
#pragma unroll
  for (int j = 0; j < 6; ++j) {
    s += e0[j] * W1[(size_t)(ZDIM + j) * HIDN + n];
    s += e1[j] * W1[(size_t)(ZDIM + 6 + j) * HIDN + n];
  }
  Hb[idx] = (bf16)tanhf(s);
}

// ---------- reduce GEMM2 partials + b2, update z, write zb ----------
__global__ void k_epi2(const float* __restrict__ P2, const float* __restrict__ b2,
                       float* __restrict__ z, bf16* __restrict__ zb) {
  int idx = blockIdx.x * 256 + threadIdx.x;  // 128*17728
  int n = idx % ZDIM;
  float s = b2[n];
#pragma unroll
  for (int c = 0; c < KC2; ++c) s += P2[(size_t)c * (BSZ * ZDIM) + idx];
  float v = z[idx] + s;
  z[idx] = v;
  zb[idx] = (bf16)v;
}

extern "C" void kernel_launch(void* const* d_in, const int* in_sizes, int n_in,
                              void* d_out, int out_size, void* d_ws, size_t ws_size,
                              hipStream_t stream) {
  const float* input_freq = (const float*)d_in[0];
  const int* seq = (const int*)d_in[1];
  const int* uid = (const int*)d_in[2];
  const float* cur = (const float*)d_in[3];
  const float* tar = (const float*)d_in[4];
  const float* fuse = (const float*)d_in[5];
  const float* W1 = (const float*)d_in[6];
  const float* b1 = (const float*)d_in[7];
  const float* W2 = (const float*)d_in[8];
  const float* b2 = (const float*)d_in[9];
  const int* n_poi = (const int*)d_in[10];
  float* z = (float*)d_out;

  char* ws = (char*)d_ws;
  bf16* W1t = (bf16*)ws;                              // 4096 x 17728 bf16 = 145,227,776 B
  bf16* W2t = (bf16*)(ws + 145227776);                // 17728 x 4096 bf16 = 145,227,776 B
  bf16* Zb = (bf16*)(ws + 290455552);                 // 128 x 17728 bf16
  bf16* Hb = (bf16*)(ws + 294993920);                 // 128 x 4096 bf16
  float* P = (float*)(ws + 296042496);                // KC1 x 128 x 4096 f32 = 33,554,432 B
  float* P2 = (float*)(ws + 296042496 + 33554432);    // KC2 x 128 x 17728 f32 = 36,306,944 B
  float* E = (float*)(ws + 296042496 + 33554432 + 36306944);  // 12 x 128 x 6 f32

  k_cast_transpose<<<dim3(HIDN / 32, ZDIM / 64), dim3(32, 8), 0, stream>>>(W1, W1t, ZDIM, HIDN);
  k_cast_transpose<<<dim3(ZDIM / 32, HIDN / 64), dim3(32, 8), 0, stream>>>(W2, W2t, HIDN, ZDIM);
  k_build_z0<<<BSZ, 256, 0, stream>>>(input_freq, seq, uid, fuse, n_poi, z, Zb);
  k_build_emb<<<1, BSZ, 0, stream>>>(cur, tar, E);

  for (int s = 0; s < 11; ++s) {
    // GEMM1: 554 k-steps = KC1*34 + 10
    k_gemm_rr<<<dim3(HIDN / 64, KC1), 256, 0, stream>>>(Zb, W1t, P, ZDIM, HIDN, 34, 10);
    k_epi1<<<2048, 256, 0, stream>>>(P, b1, W1, E, s, Hb);
    // GEMM2: 128 k-steps = KC2*32
    k_gemm_rr<<<dim3(ZDIM / 64, KC2), 256, 0, stream>>>(Hb, W2t, P2, HIDN, ZDIM, 32, 0);
    k_epi2<<<8864, 256, 0, stream>>>(P2, b2, z, Zb);
  }
}